// Round 8
// baseline (220.650 us; speedup 1.0000x reference)
//
#include <hip/hip_runtime.h>

#define Bb 4
#define Tt 2048
#define Cc 1024
#define Hh 16
#define NQKV 3072
#define Mtot 8192

typedef __bf16 bf16_t;
typedef unsigned short u16;
typedef __bf16 bf16x8 __attribute__((ext_vector_type(8)));
typedef __bf16 bf16x4 __attribute__((ext_vector_type(4)));
typedef short short4v __attribute__((ext_vector_type(4)));
typedef float f32x4 __attribute__((ext_vector_type(4)));
typedef float f32x16 __attribute__((ext_vector_type(16)));
typedef unsigned uint2v __attribute__((ext_vector_type(2)));

union bfu { bf16_t b; u16 u; };
union trpair { short4v h[2]; bf16x8 v; };
union pfu { unsigned u[4]; bf16x8 v; };

#define QSCALE 0.18033688011112042f  /* 0.125 * log2(e) */

// hardware transpose read; "memory" clobber keeps it ordered vs ds_writes
#define TRD(dst, addr, OFF)                                                     \
  asm volatile("ds_read_b64_tr_b16 %0, %1 offset:" OFF                          \
               : "=v"(dst) : "v"(addr) : "memory")

__device__ __forceinline__ unsigned cvtpk(float a, float b) {
  unsigned r;
  asm("v_cvt_pk_bf16_f32 %0, %1, %2" : "=v"(r) : "v"(a), "v"(b));
  return r;
}
__device__ __forceinline__ uint2v plswap(unsigned a, unsigned b) {
  return __builtin_amdgcn_permlane32_swap(a, b, false, false);
}

// ---------------------------------------------------------------------------
// f32 -> bf16 conversion; elements with idx < nscale multiplied by factor
// ---------------------------------------------------------------------------
__global__ __launch_bounds__(256) void cvt_f32_bf16(const float* __restrict__ s,
                                                    u16* __restrict__ d,
                                                    long nscale, float factor) {
  size_t i = ((size_t)blockIdx.x * 256 + threadIdx.x) * 8;
  const float f = ((long)i < nscale) ? factor : 1.0f;
  float4 a = *(const float4*)(s + i);
  float4 b = *(const float4*)(s + i + 4);
  bf16x8 v;
  v[0]=(bf16_t)(a.x*f); v[1]=(bf16_t)(a.y*f); v[2]=(bf16_t)(a.z*f); v[3]=(bf16_t)(a.w*f);
  v[4]=(bf16_t)(b.x*f); v[5]=(bf16_t)(b.y*f); v[6]=(bf16_t)(b.z*f); v[7]=(bf16_t)(b.w*f);
  *(bf16x8*)(d + i) = v;
}

__global__ __launch_bounds__(256) void scale_bias(const float* __restrict__ s,
                                                  float* __restrict__ d) {
  int i = blockIdx.x * 256 + threadIdx.x;  // 3072 total
  d[i] = s[i] * ((i < Cc) ? QSCALE : 1.0f);
}

// ---------------------------------------------------------------------------
// GEMM NT, bf16 inputs, reg-staged with preload (r4 version — measured faster
// than the gload_lds variant in this pipeline by ~5 us).
// ---------------------------------------------------------------------------
template <int OUTBF16>
__global__ __launch_bounds__(256) void gemm_bf16(
    const u16* __restrict__ A, const u16* __restrict__ Bm,
    const float* __restrict__ bias, void* __restrict__ Cout,
    int M, int N, int K)
{
  __shared__ __attribute__((aligned(16))) u16 sa[128][40];
  __shared__ __attribute__((aligned(16))) u16 sb[128][40];

  const int tid  = threadIdx.x;
  const int lane = tid & 63;
  const int wid  = tid >> 6;
  const int wr   = (wid >> 1) * 64;
  const int wc   = (wid & 1) * 64;
  const int l15  = lane & 15;
  const int lh   = lane >> 4;
  const int bm   = blockIdx.x * 128;
  const int bn   = blockIdx.y * 128;

  f32x4 acc[4][4] = {};

  const int srow = tid >> 1;
  const int sseg = (tid & 1) * 16;

  const u16* pa = A  + (size_t)(bm + srow) * K + sseg;
  const u16* pb = Bm + (size_t)(bn + srow) * K + sseg;

  uint4 ar0 = *(const uint4*)pa, ar1 = *(const uint4*)(pa + 8);
  uint4 br0 = *(const uint4*)pb, br1 = *(const uint4*)(pb + 8);
  pa += 32; pb += 32;

  for (int k0 = 0; k0 < K; k0 += 32) {
    __syncthreads();
    *(uint4*)&sa[srow][sseg]     = ar0;
    *(uint4*)&sa[srow][sseg + 8] = ar1;
    *(uint4*)&sb[srow][sseg]     = br0;
    *(uint4*)&sb[srow][sseg + 8] = br1;
    __syncthreads();
    if (k0 + 32 < K) {
      ar0 = *(const uint4*)pa; ar1 = *(const uint4*)(pa + 8);
      br0 = *(const uint4*)pb; br1 = *(const uint4*)(pb + 8);
      pa += 32; pb += 32;
    }
    bf16x8 af[4], bfv[4];
#pragma unroll
    for (int mi = 0; mi < 4; mi++)
      af[mi] = *(const bf16x8*)&sa[wr + mi*16 + l15][lh * 8];
#pragma unroll
    for (int ni = 0; ni < 4; ni++)
      bfv[ni] = *(const bf16x8*)&sb[wc + ni*16 + l15][lh * 8];
#pragma unroll
    for (int mi = 0; mi < 4; mi++)
#pragma unroll
      for (int ni = 0; ni < 4; ni++)
        acc[mi][ni] = __builtin_amdgcn_mfma_f32_16x16x32_bf16(
            af[mi], bfv[ni], acc[mi][ni], 0, 0, 0);
  }

#pragma unroll
  for (int mi = 0; mi < 4; mi++) {
#pragma unroll
    for (int ni = 0; ni < 4; ni++) {
      const int col = bn + wc + ni*16 + l15;
      const float bs = bias[col];
#pragma unroll
      for (int r = 0; r < 4; r++) {
        const int row = bm + wr + mi*16 + lh*4 + r;
        const float val = acc[mi][ni][r] + bs;
        if (OUTBF16) {
          bfu cv; cv.b = (bf16_t)val;
          ((u16*)Cout)[(size_t)row * N + col] = cv.u;
        } else {
          ((float*)Cout)[(size_t)row * N + col] = val;
        }
      }
    }
  }
}

// ---------------------------------------------------------------------------
// Causal flash attention, T12 structure at 32x32 MFMA, KVBLK=128.
// Grid (8, B*H): block = q-tile pair {x, 15-x}, 17 uniform 128-key tiles.
// LDS (u16): K [0,9216) as [128 key][72 d-pad]; V [9216,18432) same layout.
// S^T = mfma(K,Q): q = lane&31; keys = (reg&3)+8*(reg>>2)+4*(lane>>5) + 32*blk.
// Softmax per-lane scalar (m,l); P packed in-register (cvt_pk + permlane32).
// O^T = mfma(V^T via tr-reads, P), 4 sections of {8 TRD, pack, 4 MFMA}.
// Q prescaled by 0.125*log2e (folded into Wq/bq).
// ---------------------------------------------------------------------------
#define VBYTE 18432   /* V region byte offset */

// one PV section: V k-slots {2i,2i+1} with P from s-block i
#define PVSEC(SV, A0,A1,A2,A3, A4,A5,A6,A7) do {                                \
  short4v t0,t1,t2,t3,t4,t5,t6,t7;                                              \
  TRD(t0, vaddr, A0); TRD(t1, vaddr, A1); TRD(t2, vaddr, A2);                   \
  TRD(t3, vaddr, A3); TRD(t4, vaddr, A4); TRD(t5, vaddr, A5);                   \
  TRD(t6, vaddr, A6); TRD(t7, vaddr, A7);                                       \
  pfu pfa, pfb;                                                                 \
  {                                                                             \
    float pe[16];                                                               \
    _Pragma("unroll")                                                           \
    for (int r = 0; r < 16; ++r) { pe[r] = exp2f(SV[r] - m_run); l_part += pe[r]; } \
    unsigned a0=cvtpk(pe[0],pe[1]),   a1=cvtpk(pe[2],pe[3]);                    \
    unsigned a2=cvtpk(pe[4],pe[5]),   a3=cvtpk(pe[6],pe[7]);                    \
    uint2v x1=plswap(a0,a2), x2=plswap(a1,a3);                                  \
    pfa.u[0]=x1[0]; pfa.u[1]=x2[0]; pfa.u[2]=x1[1]; pfa.u[3]=x2[1];             \
    unsigned b0=cvtpk(pe[8],pe[9]),   b1=cvtpk(pe[10],pe[11]);                  \
    unsigned b2=cvtpk(pe[12],pe[13]), b3=cvtpk(pe[14],pe[15]);                  \
    uint2v x3=plswap(b0,b2), x4=plswap(b1,b3);                                  \
    pfb.u[0]=x3[0]; pfb.u[1]=x4[0]; pfb.u[2]=x3[1]; pfb.u[3]=x4[1];             \
  }                                                                             \
  asm volatile("s_waitcnt lgkmcnt(0)" ::: "memory");                            \
  __builtin_amdgcn_sched_barrier(0);                                            \
  trpair va,vb,vc,vd;                                                           \
  va.h[0]=t0; va.h[1]=t1;  vb.h[0]=t2; vb.h[1]=t3;                              \
  vc.h[0]=t4; vc.h[1]=t5;  vd.h[0]=t6; vd.h[1]=t7;                              \
  o0 = __builtin_amdgcn_mfma_f32_32x32x16_bf16(va.v, pfa.v, o0, 0,0,0);         \
  o1 = __builtin_amdgcn_mfma_f32_32x32x16_bf16(vb.v, pfa.v, o1, 0,0,0);         \
  o0 = __builtin_amdgcn_mfma_f32_32x32x16_bf16(vc.v, pfb.v, o0, 0,0,0);         \
  o1 = __builtin_amdgcn_mfma_f32_32x32x16_bf16(vd.v, pfb.v, o1, 0,0,0);         \
} while (0)

__global__ __launch_bounds__(256) void attn_kernel(
    const u16* __restrict__ qkv, u16* __restrict__ y)
{
  __shared__ __attribute__((aligned(16))) u16 smem[18432];   // 36 KB

  const int tid  = threadIdx.x;
  const int lane = tid & 63;
  const int w    = tid >> 6;
  const int l31  = lane & 31;
  const int hh   = lane >> 5;
  const int l15  = lane & 15;
  const int lh   = lane >> 4;
  const int bh   = blockIdx.y;
  const int b    = bh >> 4;
  const int head = bh & 15;

  const size_t rowbase = (size_t)b * Tt * NQKV;

  // staging map: 64B of one key row per thread (2 threads/row)
  const int skey = tid >> 1;          // 0..127
  const int sp   = tid & 1;           // col offset sp*32 (u16)
  const u16* kbase = qkv + rowbase + 1024 + head*64 + sp*32;
  const u16* vbase = qkv + rowbase + 2048 + head*64 + sp*32;

  // V^T tr-read lane address (bytes)
  const unsigned smemB = (unsigned)(size_t)(&smem[0]);
  const unsigned vaddr = smemB + VBYTE
      + ((lh>>1)*8 + (l15>>2))*144 + (lh&1)*32 + (l15&3)*8;

  for (int half = 0; half < 2; ++half) {
    const int qb    = half ? (15 - (int)blockIdx.x) : (int)blockIdx.x;
    const int qbase = qb * 128;
    const int qw    = qbase + w * 32;
    const int qi    = qw + l31;            // this lane's q row
    const int ktiles = qb + 1;             // 128-key tiles

    // Q fragments (B operand): lane holds Q[qi][m*16 + hh*8 + j]
    bf16x8 qfrag[4];
#pragma unroll
    for (int m = 0; m < 4; ++m)
      qfrag[m] = *(const bf16x8*)(qkv + rowbase + (size_t)qi * NQKV
                                  + head*64 + m*16 + hh*8);

    f32x16 o0 = {}, o1 = {};               // O^T: d 0..31 / d 32..63
    float m_run = -1e30f, l_part = 0.0f;

    uint4 kr0, kr1, kr2, kr3, vr0, vr1, vr2, vr3;
    {
      const u16* kp = kbase + (size_t)skey * NQKV;
      const u16* vp = vbase + (size_t)skey * NQKV;
      kr0 = ((const uint4*)kp)[0]; kr1 = ((const uint4*)kp)[1];
      kr2 = ((const uint4*)kp)[2]; kr3 = ((const uint4*)kp)[3];
      vr0 = ((const uint4*)vp)[0]; vr1 = ((const uint4*)vp)[1];
      vr2 = ((const uint4*)vp)[2]; vr3 = ((const uint4*)vp)[3];
    }

    for (int kt = 0; kt < ktiles; ++kt) {
      __syncthreads();   // also orders prev-half epilogue reads vs staging
      {
        u16* dK = &smem[skey*72 + sp*32];
        *(uint4*)dK        = kr0; *(uint4*)(dK + 8)  = kr1;
        *(uint4*)(dK + 16) = kr2; *(uint4*)(dK + 24) = kr3;
        u16* dV = dK + 9216;
        *(uint4*)dV        = vr0; *(uint4*)(dV + 8)  = vr1;
        *(uint4*)(dV + 16) = vr2; *(uint4*)(dV + 24) = vr3;
      }
      __syncthreads();

      if (kt + 1 < ktiles) {  // T14: issue next tile's loads before compute
        const u16* kp = kbase + (size_t)((kt+1)*128 + skey) * NQKV;
        const u16* vp = vbase + (size_t)((kt+1)*128 + skey) * NQKV;
        kr0 = ((const uint4*)kp)[0]; kr1 = ((const uint4*)kp)[1];
        kr2 = ((const uint4*)kp)[2]; kr3 = ((const uint4*)kp)[3];
        vr0 = ((const uint4*)vp)[0]; vr1 = ((const uint4*)vp)[1];
        vr2 = ((const uint4*)vp)[2]; vr3 = ((const uint4*)vp)[3];
      }

      // ---- S^T = K Q^T : four 32-key blocks ----
      f32x16 s0 = {}, s1 = {}, s2 = {}, s3 = {};
#pragma unroll
      for (int m = 0; m < 4; ++m) {
        const int co = m*16 + hh*8;
        bf16x8 k0 = *(const bf16x8*)&smem[(l31)*72      + co];
        bf16x8 k1 = *(const bf16x8*)&smem[(32 + l31)*72 + co];
        bf16x8 k2 = *(const bf16x8*)&smem[(64 + l31)*72 + co];
        bf16x8 k3 = *(const bf16x8*)&smem[(96 + l31)*72 + co];
        s0 = __builtin_amdgcn_mfma_f32_32x32x16_bf16(k0, qfrag[m], s0, 0,0,0);
        s1 = __builtin_amdgcn_mfma_f32_32x32x16_bf16(k1, qfrag[m], s1, 0,0,0);
        s2 = __builtin_amdgcn_mfma_f32_32x32x16_bf16(k2, qfrag[m], s2, 0,0,0);
        s3 = __builtin_amdgcn_mfma_f32_32x32x16_bf16(k3, qfrag[m], s3, 0,0,0);
      }

      // ---- causal mask (diagonal tile only: kt == qb) ----
      if (kt*128 + 127 > qw) {
        const int kb0 = kt*128;
#pragma unroll
        for (int r = 0; r < 16; ++r) {
          const int crow = (r&3) + 8*(r>>2) + 4*hh;
          if (kb0 + crow > qi)      s0[r] = -1e30f;
          if (kb0 + 32 + crow > qi) s1[r] = -1e30f;
          if (kb0 + 64 + crow > qi) s2[r] = -1e30f;
          if (kb0 + 96 + crow > qi) s3[r] = -1e30f;
        }
      }

      // ---- per-lane softmax: tree max + one permlane swap ----
      float ma[16];
#pragma unroll
      for (int r = 0; r < 16; ++r)
        ma[r] = fmaxf(fmaxf(s0[r], s1[r]), fmaxf(s2[r], s3[r]));
      float t8[8], t4[4], t2[2];
#pragma unroll
      for (int i = 0; i < 8; ++i) t8[i] = fmaxf(ma[i], ma[i+8]);
#pragma unroll
      for (int i = 0; i < 4; ++i) t4[i] = fmaxf(t8[i], t8[i+4]);
      t2[0] = fmaxf(t4[0], t4[2]); t2[1] = fmaxf(t4[1], t4[3]);
      float rm = fmaxf(t2[0], t2[1]);
      {
        uint2v t = plswap(__float_as_uint(rm), __float_as_uint(rm));
        rm = fmaxf(__uint_as_float(t[0]), __uint_as_float(t[1]));
      }
      if (__any(rm > m_run + 8.0f)) {      // defer-max THR=8 (log2 units)
        const float mn = fmaxf(m_run, rm);
        const float al = exp2f(m_run - mn);
        m_run = mn; l_part *= al;
#pragma unroll
        for (int r = 0; r < 16; ++r) { o0[r] *= al; o1[r] *= al; }
      }

      // ---- 4 PV sections: {8 tr-reads | exp+pack | wait | 4 MFMA} ----
      PVSEC(s0, "0","576","64","640",          "2304","2880","2368","2944");
      PVSEC(s1, "4608","5184","4672","5248",   "6912","7488","6976","7552");
      PVSEC(s2, "9216","9792","9280","9856",   "11520","12096","11584","12160");
      PVSEC(s3, "13824","14400","13888","14464","16128","16704","16192","16768");
    }

    // ---- epilogue ----
    {
      uint2v t = plswap(__float_as_uint(l_part), __float_as_uint(l_part));
      l_part = __uint_as_float(t[0]) + __uint_as_float(t[1]);
    }
    const float inv = 1.0f / l_part;

    __syncthreads();   // all waves done with K/V before scratch reuse
#pragma unroll
    for (int k4 = 0; k4 < 4; ++k4) {
      bf16x4 pa, pb;
#pragma unroll
      for (int j = 0; j < 4; ++j) {
        pa[j] = (bf16_t)(o0[4*k4 + j] * inv);
        pb[j] = (bf16_t)(o1[4*k4 + j] * inv);
      }
      *(bf16x4*)&smem[w*2304 + l31*72 +      8*k4 + 4*hh] = pa;
      *(bf16x4*)&smem[w*2304 + l31*72 + 32 + 8*k4 + 4*hh] = pb;
    }
    u16* yp = y + ((size_t)(b*Tt + qi)) * Cc + head*64;
#pragma unroll
    for (int p = 0; p < 4; ++p) {
      bf16x8 row = *(const bf16x8*)&smem[w*2304 + l31*72 + p*16 + hh*8];
      *(bf16x8*)(yp + p*16 + hh*8) = row;
    }
  }
}

// ---------------------------------------------------------------------------
extern "C" void kernel_launch(void* const* d_in, const int* in_sizes, int n_in,
                              void* d_out, int out_size, void* d_ws, size_t ws_size,
                              hipStream_t stream) {
  const float* x      = (const float*)d_in[0];
  const float* w_attn = (const float*)d_in[1];
  const float* b_attn = (const float*)d_in[2];
  const float* w_proj = (const float*)d_in[3];
  const float* b_proj = (const float*)d_in[4];
  float* out = (float*)d_out;

  char* ws = (char*)d_ws;
  u16*   xb    = (u16*)(ws + 0);          // 16 MB
  u16*   wab   = (u16*)(ws + 16777216);   // 6 MB
  u16*   wpb   = (u16*)(ws + 23068672);   // 2 MB
  u16*   qkvb  = (u16*)(ws + 25165824);   // 48 MB
  u16*   yb    = (u16*)(ws + 75497472);   // 16 MB
  float* sbias = (float*)(ws + 92274688); // 12 KB

  // convert inputs to bf16; fold 0.125*log2e into Wq rows and bq
  cvt_f32_bf16<<<4096, 256, 0, stream>>>(x,      xb,  0, 1.0f);
  cvt_f32_bf16<<<1536, 256, 0, stream>>>(w_attn, wab, (long)Cc*Cc, QSCALE);
  cvt_f32_bf16<<<512,  256, 0, stream>>>(w_proj, wpb, 0, 1.0f);
  scale_bias<<<12, 256, 0, stream>>>(b_attn, sbias);

  // 1) QKV projection (bf16 out, q pre-scaled)
  gemm_bf16<1><<<dim3(Mtot/128, NQKV/128), 256, 0, stream>>>(
      xb, wab, sbias, (void*)qkvb, Mtot, NQKV, Cc);

  // 2) causal attention (bf16 y) — paired q-tiles, 17 uniform 128-key tiles
  attn_kernel<<<dim3(8, Bb*Hh), 256, 0, stream>>>(qkvb, yb);

  // 3) output projection (f32 out)
  gemm_bf16<0><<<dim3(Mtot/128, Cc/128), 256, 0, stream>>>(
      yb, wpb, b_proj, (void*)out, Mtot, Cc, Cc);
}

// Round 9
// 198.319 us; speedup vs baseline: 1.1126x; 1.1126x over previous
//
#include <hip/hip_runtime.h>

#define Bb 4
#define Tt 2048
#define Cc 1024
#define Hh 16
#define NQKV 3072
#define Mtot 8192

typedef __bf16 bf16_t;
typedef unsigned short u16;
typedef __bf16 bf16x8 __attribute__((ext_vector_type(8)));
typedef __bf16 bf16x4 __attribute__((ext_vector_type(4)));
typedef short short4v __attribute__((ext_vector_type(4)));
typedef float f32x4 __attribute__((ext_vector_type(4)));
typedef float f32x16 __attribute__((ext_vector_type(16)));
typedef unsigned uint2v __attribute__((ext_vector_type(2)));

union bfu { bf16_t b; u16 u; };
union trpair { short4v h[2]; bf16x8 v; };
union pfu { unsigned u[4]; bf16x8 v; };
union o16 { f32x16 v; f32x4 q[4]; };

#define QSCALE 0.18033688011112042f  /* 0.125 * log2(e) */

// hardware transpose read; "memory" clobber keeps it ordered vs ds_writes
#define TRD(dst, addr, OFF)                                                     \
  asm volatile("ds_read_b64_tr_b16 %0, %1 offset:" OFF                          \
               : "=v"(dst) : "v"(addr) : "memory")

__device__ __forceinline__ unsigned cvtpk(float a, float b) {
  unsigned r;
  asm("v_cvt_pk_bf16_f32 %0, %1, %2" : "=v"(r) : "v"(a), "v"(b));
  return r;
}
__device__ __forceinline__ uint2v plswap(unsigned a, unsigned b) {
  return __builtin_amdgcn_permlane32_swap(a, b, false, false);
}

// ---------------------------------------------------------------------------
// f32 -> bf16 conversion; elements with idx < nscale multiplied by factor
// ---------------------------------------------------------------------------
__global__ __launch_bounds__(256) void cvt_f32_bf16(const float* __restrict__ s,
                                                    u16* __restrict__ d,
                                                    long nscale, float factor) {
  size_t i = ((size_t)blockIdx.x * 256 + threadIdx.x) * 8;
  const float f = ((long)i < nscale) ? factor : 1.0f;
  float4 a = *(const float4*)(s + i);
  float4 b = *(const float4*)(s + i + 4);
  bf16x8 v;
  v[0]=(bf16_t)(a.x*f); v[1]=(bf16_t)(a.y*f); v[2]=(bf16_t)(a.z*f); v[3]=(bf16_t)(a.w*f);
  v[4]=(bf16_t)(b.x*f); v[5]=(bf16_t)(b.y*f); v[6]=(bf16_t)(b.z*f); v[7]=(bf16_t)(b.w*f);
  *(bf16x8*)(d + i) = v;
}

__global__ __launch_bounds__(256) void scale_bias(const float* __restrict__ s,
                                                  float* __restrict__ d) {
  int i = blockIdx.x * 256 + threadIdx.x;  // 3072 total
  d[i] = s[i] * ((i < Cc) ? QSCALE : 1.0f);
}

// ---------------------------------------------------------------------------
// GEMM NT, bf16 inputs, reg-staged with preload (r4 version — fastest measured)
// ---------------------------------------------------------------------------
template <int OUTBF16>
__global__ __launch_bounds__(256) void gemm_bf16(
    const u16* __restrict__ A, const u16* __restrict__ Bm,
    const float* __restrict__ bias, void* __restrict__ Cout,
    int M, int N, int K)
{
  __shared__ __attribute__((aligned(16))) u16 sa[128][40];
  __shared__ __attribute__((aligned(16))) u16 sb[128][40];

  const int tid  = threadIdx.x;
  const int lane = tid & 63;
  const int wid  = tid >> 6;
  const int wr   = (wid >> 1) * 64;
  const int wc   = (wid & 1) * 64;
  const int l15  = lane & 15;
  const int lh   = lane >> 4;
  const int bm   = blockIdx.x * 128;
  const int bn   = blockIdx.y * 128;

  f32x4 acc[4][4] = {};

  const int srow = tid >> 1;
  const int sseg = (tid & 1) * 16;

  const u16* pa = A  + (size_t)(bm + srow) * K + sseg;
  const u16* pb = Bm + (size_t)(bn + srow) * K + sseg;

  uint4 ar0 = *(const uint4*)pa, ar1 = *(const uint4*)(pa + 8);
  uint4 br0 = *(const uint4*)pb, br1 = *(const uint4*)(pb + 8);
  pa += 32; pb += 32;

  for (int k0 = 0; k0 < K; k0 += 32) {
    __syncthreads();
    *(uint4*)&sa[srow][sseg]     = ar0;
    *(uint4*)&sa[srow][sseg + 8] = ar1;
    *(uint4*)&sb[srow][sseg]     = br0;
    *(uint4*)&sb[srow][sseg + 8] = br1;
    __syncthreads();
    if (k0 + 32 < K) {
      ar0 = *(const uint4*)pa; ar1 = *(const uint4*)(pa + 8);
      br0 = *(const uint4*)pb; br1 = *(const uint4*)(pb + 8);
      pa += 32; pb += 32;
    }
    bf16x8 af[4], bfv[4];
#pragma unroll
    for (int mi = 0; mi < 4; mi++)
      af[mi] = *(const bf16x8*)&sa[wr + mi*16 + l15][lh * 8];
#pragma unroll
    for (int ni = 0; ni < 4; ni++)
      bfv[ni] = *(const bf16x8*)&sb[wc + ni*16 + l15][lh * 8];
#pragma unroll
    for (int mi = 0; mi < 4; mi++)
#pragma unroll
      for (int ni = 0; ni < 4; ni++)
        acc[mi][ni] = __builtin_amdgcn_mfma_f32_16x16x32_bf16(
            af[mi], bfv[ni], acc[mi][ni], 0, 0, 0);
  }

#pragma unroll
  for (int mi = 0; mi < 4; mi++) {
#pragma unroll
    for (int ni = 0; ni < 4; ni++) {
      const int col = bn + wc + ni*16 + l15;
      const float bs = bias[col];
#pragma unroll
      for (int r = 0; r < 4; r++) {
        const int row = bm + wr + mi*16 + lh*4 + r;
        const float val = acc[mi][ni][r] + bs;
        if (OUTBF16) {
          bfu cv; cv.b = (bf16_t)val;
          ((u16*)Cout)[(size_t)row * N + col] = cv.u;
        } else {
          ((float*)Cout)[(size_t)row * N + col] = val;
        }
      }
    }
  }
}

// ---------------------------------------------------------------------------
// Causal flash attention: 8-wave blocks, KVBLK=128 split 64/64 across wave
// pairs; per-wave pipeline identical to r5 (32q x 64k, T12 in-reg softmax).
// Grid (8, B*H): block = q-tile pair {x, 15-x}; per half ktiles = qb+1 (17
// total per block — uniform). Waves 0-3 = keys [0,64) of each tile (hw=0),
// waves 4-7 = keys [64,128) (hw=1); wave w handles q-chunk (w&3).
// End of half: hw=1 waves write (m,l,O^T) to LDS; hw=0 waves merge + store y.
// LDS (u16): K [0,9216) = [128 key][72 d-pad]; V [9216,18432) same.
// Q prescaled by 0.125*log2e (folded into Wq/bq).
// ---------------------------------------------------------------------------
__global__ __launch_bounds__(512, 4) void attn_kernel(
    const u16* __restrict__ qkv, u16* __restrict__ y)
{
  __shared__ __attribute__((aligned(16))) u16 smem[18432];   // 36 KB

  const int tid  = threadIdx.x;
  const int lane = tid & 63;
  const int w    = tid >> 6;          // 0..7
  const int hw   = w >> 2;            // key-half
  const int ch   = w & 3;             // q-chunk
  const int l31  = lane & 31;
  const int hh   = lane >> 5;
  const int l15  = lane & 15;
  const int lh   = lane >> 4;
  const int bh   = blockIdx.y;
  const int b    = bh >> 4;
  const int head = bh & 15;

  const size_t rowbase = (size_t)b * Tt * NQKV;

  // staging map: 32B of one key row per thread (4 threads/row, 128 rows)
  const int skey = tid >> 2;          // 0..127
  const int sp   = tid & 3;           // col sp*16 u16
  const u16* kbase = qkv + rowbase + 1024 + head*64 + sp*16;
  const u16* vbase = qkv + rowbase + 2048 + head*64 + sp*16;

  // V^T tr-read lane address (bytes): V region + this wave's 64-row window
  const unsigned smemB = (unsigned)(size_t)(&smem[0]);
  const unsigned vaddr = smemB + 18432 + hw*9216
      + ((lh>>1)*8 + (l15>>2))*144 + (lh&1)*32 + (l15&3)*8;

  for (int half = 0; half < 2; ++half) {
    const int qb    = half ? (15 - (int)blockIdx.x) : (int)blockIdx.x;
    const int qbase = qb * 128;
    const int qw    = qbase + ch * 32;
    const int qi    = qw + l31;            // this lane's q row
    const int ktiles = qb + 1;             // 128-key tiles

    // Q fragments (B operand): lane holds Q[qi][m*16 + hh*8 + j]
    bf16x8 qfrag[4];
#pragma unroll
    for (int m = 0; m < 4; ++m)
      qfrag[m] = *(const bf16x8*)(qkv + rowbase + (size_t)qi * NQKV
                                  + head*64 + m*16 + hh*8);

    f32x16 o0 = {}, o1 = {};               // O^T: d 0..31 / d 32..63
    float m_run = -1e30f, l_part = 0.0f;

    uint4 kr0, kr1, vr0, vr1;
    {
      const u16* kp = kbase + (size_t)skey * NQKV;
      const u16* vp = vbase + (size_t)skey * NQKV;
      kr0 = ((const uint4*)kp)[0]; kr1 = ((const uint4*)kp)[1];
      vr0 = ((const uint4*)vp)[0]; vr1 = ((const uint4*)vp)[1];
    }

    for (int kt = 0; kt < ktiles; ++kt) {
      __syncthreads();   // prev iter reads done / prev half merge+epi done
      *(uint4*)&smem[skey*72 + sp*16]          = kr0;
      *(uint4*)&smem[skey*72 + sp*16 + 8]      = kr1;
      *(uint4*)&smem[9216 + skey*72 + sp*16]   = vr0;
      *(uint4*)&smem[9216 + skey*72 + sp*16+8] = vr1;
      __syncthreads();

      if (kt + 1 < ktiles) {  // T14: issue next tile's loads before compute
        const u16* kp = kbase + (size_t)((kt+1)*128 + skey) * NQKV;
        const u16* vp = vbase + (size_t)((kt+1)*128 + skey) * NQKV;
        kr0 = ((const uint4*)kp)[0]; kr1 = ((const uint4*)kp)[1];
        vr0 = ((const uint4*)vp)[0]; vr1 = ((const uint4*)vp)[1];
      }

      const int keyw = kt*128 + hw*64;   // this wave's key-window start
      if (keyw <= qw + 31) {
        // ---- S^T = K Q^T : two 32-key blocks of this wave's window ----
        f32x16 s0 = {}, s1 = {};
#pragma unroll
        for (int m = 0; m < 4; ++m) {
          const int co = m*16 + hh*8;
          bf16x8 k0 = *(const bf16x8*)&smem[(hw*64 +      l31)*72 + co];
          bf16x8 k1 = *(const bf16x8*)&smem[(hw*64 + 32 + l31)*72 + co];
          s0 = __builtin_amdgcn_mfma_f32_32x32x16_bf16(k0, qfrag[m], s0, 0,0,0);
          s1 = __builtin_amdgcn_mfma_f32_32x32x16_bf16(k1, qfrag[m], s1, 0,0,0);
        }

        // ---- causal mask ----
        if (keyw + 63 > qw) {
#pragma unroll
          for (int r = 0; r < 16; ++r) {
            const int crow = (r&3) + 8*(r>>2) + 4*hh;
            if (keyw + crow > qi)      s0[r] = -1e30f;
            if (keyw + 32 + crow > qi) s1[r] = -1e30f;
          }
        }

        // ---- per-lane softmax: in-lane max + one permlane swap ----
        float rm = s0[0];
#pragma unroll
        for (int r = 1; r < 16; ++r) rm = fmaxf(rm, s0[r]);
#pragma unroll
        for (int r = 0; r < 16; ++r) rm = fmaxf(rm, s1[r]);
        {
          uint2v t = plswap(__float_as_uint(rm), __float_as_uint(rm));
          rm = fmaxf(__uint_as_float(t[0]), __uint_as_float(t[1]));
        }
        if (__any(rm > m_run + 8.0f)) {    // defer-max THR=8 (log2 units)
          const float mn = fmaxf(m_run, rm);
          const float al = exp2f(m_run - mn);
          m_run = mn; l_part *= al;
#pragma unroll
          for (int r = 0; r < 16; ++r) { o0[r] *= al; o1[r] *= al; }
        }

        // ---- exp2 + in-register P pack (T12) ----
        pfu pf0, pf1, pf2, pf3;
        {
          float pe[16];
#pragma unroll
          for (int r = 0; r < 16; ++r) { pe[r] = exp2f(s0[r] - m_run); l_part += pe[r]; }
          unsigned a0 = cvtpk(pe[0],pe[1]),  a1 = cvtpk(pe[2],pe[3]);
          unsigned a2 = cvtpk(pe[4],pe[5]),  a3 = cvtpk(pe[6],pe[7]);
          uint2v x1 = plswap(a0, a2), x2 = plswap(a1, a3);
          pf0.u[0]=x1[0]; pf0.u[1]=x2[0]; pf0.u[2]=x1[1]; pf0.u[3]=x2[1];
          unsigned b0 = cvtpk(pe[8],pe[9]),  b1 = cvtpk(pe[10],pe[11]);
          unsigned b2 = cvtpk(pe[12],pe[13]), b3 = cvtpk(pe[14],pe[15]);
          uint2v x3 = plswap(b0, b2), x4 = plswap(b1, b3);
          pf1.u[0]=x3[0]; pf1.u[1]=x4[0]; pf1.u[2]=x3[1]; pf1.u[3]=x4[1];
        }
        {
          float pe[16];
#pragma unroll
          for (int r = 0; r < 16; ++r) { pe[r] = exp2f(s1[r] - m_run); l_part += pe[r]; }
          unsigned a0 = cvtpk(pe[0],pe[1]),  a1 = cvtpk(pe[2],pe[3]);
          unsigned a2 = cvtpk(pe[4],pe[5]),  a3 = cvtpk(pe[6],pe[7]);
          uint2v x1 = plswap(a0, a2), x2 = plswap(a1, a3);
          pf2.u[0]=x1[0]; pf2.u[1]=x2[0]; pf2.u[2]=x1[1]; pf2.u[3]=x2[1];
          unsigned b0 = cvtpk(pe[8],pe[9]),  b1 = cvtpk(pe[10],pe[11]);
          unsigned b2 = cvtpk(pe[12],pe[13]), b3 = cvtpk(pe[14],pe[15]);
          uint2v x3 = plswap(b0, b2), x4 = plswap(b1, b3);
          pf3.u[0]=x3[0]; pf3.u[1]=x4[0]; pf3.u[2]=x3[1]; pf3.u[3]=x4[1];
        }

        // ---- O^T += V^T P : 16 tr-reads, then 8 MFMAs ----
        short4v ta0,tb0,ta1,tb1,ta2,tb2,ta3,tb3,ta4,tb4,ta5,tb5,ta6,tb6,ta7,tb7;
        TRD(ta0, vaddr, "0");    TRD(tb0, vaddr, "576");   // c0 d2=0
        TRD(ta1, vaddr, "64");   TRD(tb1, vaddr, "640");   // c0 d2=1
        TRD(ta2, vaddr, "2304"); TRD(tb2, vaddr, "2880");  // c1 d2=0
        TRD(ta3, vaddr, "2368"); TRD(tb3, vaddr, "2944");  // c1 d2=1
        TRD(ta4, vaddr, "4608"); TRD(tb4, vaddr, "5184");  // c2 d2=0
        TRD(ta5, vaddr, "4672"); TRD(tb5, vaddr, "5248");  // c2 d2=1
        TRD(ta6, vaddr, "6912"); TRD(tb6, vaddr, "7488");  // c3 d2=0
        TRD(ta7, vaddr, "6976"); TRD(tb7, vaddr, "7552");  // c3 d2=1
        asm volatile("s_waitcnt lgkmcnt(0)" ::: "memory");
        __builtin_amdgcn_sched_barrier(0);
        trpair v00,v01,v10,v11,v20,v21,v30,v31;
        v00.h[0]=ta0; v00.h[1]=tb0;  v01.h[0]=ta1; v01.h[1]=tb1;
        v10.h[0]=ta2; v10.h[1]=tb2;  v11.h[0]=ta3; v11.h[1]=tb3;
        v20.h[0]=ta4; v20.h[1]=tb4;  v21.h[0]=ta5; v21.h[1]=tb5;
        v30.h[0]=ta6; v30.h[1]=tb6;  v31.h[0]=ta7; v31.h[1]=tb7;
        o0 = __builtin_amdgcn_mfma_f32_32x32x16_bf16(v00.v, pf0.v, o0, 0,0,0);
        o1 = __builtin_amdgcn_mfma_f32_32x32x16_bf16(v01.v, pf0.v, o1, 0,0,0);
        o0 = __builtin_amdgcn_mfma_f32_32x32x16_bf16(v10.v, pf1.v, o0, 0,0,0);
        o1 = __builtin_amdgcn_mfma_f32_32x32x16_bf16(v11.v, pf1.v, o1, 0,0,0);
        o0 = __builtin_amdgcn_mfma_f32_32x32x16_bf16(v20.v, pf2.v, o0, 0,0,0);
        o1 = __builtin_amdgcn_mfma_f32_32x32x16_bf16(v21.v, pf2.v, o1, 0,0,0);
        o0 = __builtin_amdgcn_mfma_f32_32x32x16_bf16(v30.v, pf3.v, o0, 0,0,0);
        o1 = __builtin_amdgcn_mfma_f32_32x32x16_bf16(v31.v, pf3.v, o1, 0,0,0);
      }
    }

    // ---- merge wave pairs through LDS (region (w&3)*4608 u16, 144B/lane) ----
    __syncthreads();                       // all K/V reads done
    if (hw == 1) {
      float* p = (float*)&smem[ch*4608 + lane*72];
      p[0] = m_run; p[1] = l_part;
      o16 ua, ub; ua.v = o0; ub.v = o1;
#pragma unroll
      for (int i = 0; i < 4; ++i) {
        *(f32x4*)(p + 4  + 4*i) = ua.q[i];
        *(f32x4*)(p + 20 + 4*i) = ub.q[i];
      }
    }
    __syncthreads();
    if (hw == 0) {
      const float* p = (const float*)&smem[ch*4608 + lane*72];
      const float mB = p[0], lB = p[1];
      const float mN = fmaxf(m_run, mB);
      const float fA = exp2f(m_run - mN), fB = exp2f(mB - mN);
      l_part = l_part*fA + lB*fB;
#pragma unroll
      for (int i = 0; i < 4; ++i) {
        f32x4 qa = *(const f32x4*)(p + 4  + 4*i);
        f32x4 qb4 = *(const f32x4*)(p + 20 + 4*i);
#pragma unroll
        for (int j = 0; j < 4; ++j) {
          o0[4*i+j] = o0[4*i+j]*fA + qa[j]*fB;
          o1[4*i+j] = o1[4*i+j]*fA + qb4[j]*fB;
        }
      }

      // ---- epilogue (A-waves only): reduce l, normalize, transpose, store ----
      {
        uint2v t = plswap(__float_as_uint(l_part), __float_as_uint(l_part));
        l_part = __uint_as_float(t[0]) + __uint_as_float(t[1]);
      }
      const float inv = 1.0f / l_part;
      const int scr = ch*4608 + 2304;      // scratch inside own merge region
#pragma unroll
      for (int k4 = 0; k4 < 4; ++k4) {
        bf16x4 pa, pb;
#pragma unroll
        for (int j = 0; j < 4; ++j) {
          pa[j] = (bf16_t)(o0[4*k4 + j] * inv);
          pb[j] = (bf16_t)(o1[4*k4 + j] * inv);
        }
        *(bf16x4*)&smem[scr + l31*72 +      8*k4 + 4*hh] = pa;
        *(bf16x4*)&smem[scr + l31*72 + 32 + 8*k4 + 4*hh] = pb;
      }
      u16* yp = y + ((size_t)(b*Tt + qi)) * Cc + head*64;
#pragma unroll
      for (int pcol = 0; pcol < 4; ++pcol) {
        bf16x8 row = *(const bf16x8*)&smem[scr + l31*72 + pcol*16 + hh*8];
        *(bf16x8*)(yp + pcol*16 + hh*8) = row;
      }
    }
    // next half's loop-top __syncthreads orders merge/epilogue vs restaging
  }
}

// ---------------------------------------------------------------------------
extern "C" void kernel_launch(void* const* d_in, const int* in_sizes, int n_in,
                              void* d_out, int out_size, void* d_ws, size_t ws_size,
                              hipStream_t stream) {
  const float* x      = (const float*)d_in[0];
  const float* w_attn = (const float*)d_in[1];
  const float* b_attn = (const float*)d_in[2];
  const float* w_proj = (const float*)d_in[3];
  const float* b_proj = (const float*)d_in[4];
  float* out = (float*)d_out;

  char* ws = (char*)d_ws;
  u16*   xb    = (u16*)(ws + 0);          // 16 MB
  u16*   wab   = (u16*)(ws + 16777216);   // 6 MB
  u16*   wpb   = (u16*)(ws + 23068672);   // 2 MB
  u16*   qkvb  = (u16*)(ws + 25165824);   // 48 MB
  u16*   yb    = (u16*)(ws + 75497472);   // 16 MB
  float* sbias = (float*)(ws + 92274688); // 12 KB

  // convert inputs to bf16; fold 0.125*log2e into Wq rows and bq
  cvt_f32_bf16<<<4096, 256, 0, stream>>>(x,      xb,  0, 1.0f);
  cvt_f32_bf16<<<1536, 256, 0, stream>>>(w_attn, wab, (long)Cc*Cc, QSCALE);
  cvt_f32_bf16<<<512,  256, 0, stream>>>(w_proj, wpb, 0, 1.0f);
  scale_bias<<<12, 256, 0, stream>>>(b_attn, sbias);

  // 1) QKV projection (bf16 out, q pre-scaled)
  gemm_bf16<1><<<dim3(Mtot/128, NQKV/128), 256, 0, stream>>>(
      xb, wab, sbias, (void*)qkvb, Mtot, NQKV, Cc);

  // 2) causal attention (bf16 y) — 8-wave blocks, k-parallel wave pairs
  attn_kernel<<<dim3(8, Bb*Hh), 512, 0, stream>>>(qkvb, yb);

  // 3) output projection (f32 out)
  gemm_bf16<0><<<dim3(Mtot/128, Cc/128), 256, 0, stream>>>(
      yb, wpb, b_proj, (void*)out, Mtot, Cc, Cc);
}

// Round 10
// 184.772 us; speedup vs baseline: 1.1942x; 1.0733x over previous
//
#include <hip/hip_runtime.h>

#define Bb 4
#define Tt 2048
#define Cc 1024
#define Hh 16
#define NQKV 3072
#define Mtot 8192

typedef __bf16 bf16_t;
typedef unsigned short u16;
typedef __bf16 bf16x8 __attribute__((ext_vector_type(8)));
typedef __bf16 bf16x4 __attribute__((ext_vector_type(4)));
typedef short short4v __attribute__((ext_vector_type(4)));
typedef float f32x4 __attribute__((ext_vector_type(4)));
typedef float f32x16 __attribute__((ext_vector_type(16)));
typedef unsigned uint2v __attribute__((ext_vector_type(2)));

union bfu { bf16_t b; u16 u; };
union trpair { short4v h[2]; bf16x8 v; };
union pfu { unsigned u[4]; bf16x8 v; };

#define QSCALE 0.18033688011112042f  /* 0.125 * log2(e) */

// hardware transpose read; "memory" clobber keeps it ordered vs ds_writes
#define TRD(dst, addr, OFF)                                                     \
  asm volatile("ds_read_b64_tr_b16 %0, %1 offset:" OFF                          \
               : "=v"(dst) : "v"(addr) : "memory")

__device__ __forceinline__ unsigned cvtpk(float a, float b) {
  unsigned r;
  asm("v_cvt_pk_bf16_f32 %0, %1, %2" : "=v"(r) : "v"(a), "v"(b));
  return r;
}
__device__ __forceinline__ uint2v plswap(unsigned a, unsigned b) {
  return __builtin_amdgcn_permlane32_swap(a, b, false, false);
}

// ---------------------------------------------------------------------------
// One-launch conversion: x, w_attn (QSCALE on q rows), w_proj -> bf16;
// b_attn -> scaled f32 bias. 2048 elems per block.
// ---------------------------------------------------------------------------
__device__ __forceinline__ void cvt8(const float* s, u16* d, size_t i, float f) {
  float4 a = *(const float4*)(s + i);
  float4 b = *(const float4*)(s + i + 4);
  bf16x8 v;
  v[0]=(bf16_t)(a.x*f); v[1]=(bf16_t)(a.y*f); v[2]=(bf16_t)(a.z*f); v[3]=(bf16_t)(a.w*f);
  v[4]=(bf16_t)(b.x*f); v[5]=(bf16_t)(b.y*f); v[6]=(bf16_t)(b.z*f); v[7]=(bf16_t)(b.w*f);
  *(bf16x8*)(d + i) = v;
}

__global__ __launch_bounds__(256) void cvt_all(
    const float* __restrict__ x, const float* __restrict__ w_attn,
    const float* __restrict__ w_proj, const float* __restrict__ b_attn,
    u16* __restrict__ xb, u16* __restrict__ wab, u16* __restrict__ wpb,
    float* __restrict__ sbias)
{
  const int blk = blockIdx.x;
  if (blk < 4096) {                       // x: 8.39M elems
    size_t i = ((size_t)blk * 256 + threadIdx.x) * 8;
    cvt8(x, xb, i, 1.0f);
  } else if (blk < 5632) {                // w_attn: 3.15M elems
    size_t i = ((size_t)(blk - 4096) * 256 + threadIdx.x) * 8;
    cvt8(w_attn, wab, i, (i < (size_t)Cc * Cc) ? QSCALE : 1.0f);
  } else if (blk < 6144) {                // w_proj: 1.05M elems
    size_t i = ((size_t)(blk - 5632) * 256 + threadIdx.x) * 8;
    cvt8(w_proj, wpb, i, 1.0f);
  } else {                                // b_attn -> sbias (3072 f32)
    int i0 = (blk - 6144) * 2048 + threadIdx.x * 8;
#pragma unroll
    for (int j = 0; j < 8; ++j) {
      int i = i0 + j;
      if (i < NQKV) sbias[i] = b_attn[i] * ((i < Cc) ? QSCALE : 1.0f);
    }
  }
}

// ---------------------------------------------------------------------------
// GEMM NT, bf16 inputs, reg-staged with preload (r4 version — fastest measured)
// ---------------------------------------------------------------------------
template <int OUTBF16>
__global__ __launch_bounds__(256) void gemm_bf16(
    const u16* __restrict__ A, const u16* __restrict__ Bm,
    const float* __restrict__ bias, void* __restrict__ Cout,
    int M, int N, int K)
{
  __shared__ __attribute__((aligned(16))) u16 sa[128][40];
  __shared__ __attribute__((aligned(16))) u16 sb[128][40];

  const int tid  = threadIdx.x;
  const int lane = tid & 63;
  const int wid  = tid >> 6;
  const int wr   = (wid >> 1) * 64;
  const int wc   = (wid & 1) * 64;
  const int l15  = lane & 15;
  const int lh   = lane >> 4;
  const int bm   = blockIdx.x * 128;
  const int bn   = blockIdx.y * 128;

  f32x4 acc[4][4] = {};

  const int srow = tid >> 1;
  const int sseg = (tid & 1) * 16;

  const u16* pa = A  + (size_t)(bm + srow) * K + sseg;
  const u16* pb = Bm + (size_t)(bn + srow) * K + sseg;

  uint4 ar0 = *(const uint4*)pa, ar1 = *(const uint4*)(pa + 8);
  uint4 br0 = *(const uint4*)pb, br1 = *(const uint4*)(pb + 8);
  pa += 32; pb += 32;

  for (int k0 = 0; k0 < K; k0 += 32) {
    __syncthreads();
    *(uint4*)&sa[srow][sseg]     = ar0;
    *(uint4*)&sa[srow][sseg + 8] = ar1;
    *(uint4*)&sb[srow][sseg]     = br0;
    *(uint4*)&sb[srow][sseg + 8] = br1;
    __syncthreads();
    if (k0 + 32 < K) {
      ar0 = *(const uint4*)pa; ar1 = *(const uint4*)(pa + 8);
      br0 = *(const uint4*)pb; br1 = *(const uint4*)(pb + 8);
      pa += 32; pb += 32;
    }
    bf16x8 af[4], bfv[4];
#pragma unroll
    for (int mi = 0; mi < 4; mi++)
      af[mi] = *(const bf16x8*)&sa[wr + mi*16 + l15][lh * 8];
#pragma unroll
    for (int ni = 0; ni < 4; ni++)
      bfv[ni] = *(const bf16x8*)&sb[wc + ni*16 + l15][lh * 8];
#pragma unroll
    for (int mi = 0; mi < 4; mi++)
#pragma unroll
      for (int ni = 0; ni < 4; ni++)
        acc[mi][ni] = __builtin_amdgcn_mfma_f32_16x16x32_bf16(
            af[mi], bfv[ni], acc[mi][ni], 0, 0, 0);
  }

#pragma unroll
  for (int mi = 0; mi < 4; mi++) {
#pragma unroll
    for (int ni = 0; ni < 4; ni++) {
      const int col = bn + wc + ni*16 + l15;
      const float bs = bias[col];
#pragma unroll
      for (int r = 0; r < 4; r++) {
        const int row = bm + wr + mi*16 + lh*4 + r;
        const float val = acc[mi][ni][r] + bs;
        if (OUTBF16) {
          bfu cv; cv.b = (bf16_t)val;
          ((u16*)Cout)[(size_t)row * N + col] = cv.u;
        } else {
          ((float*)Cout)[(size_t)row * N + col] = val;
        }
      }
    }
  }
}

// ---------------------------------------------------------------------------
// Causal flash attention: r5 per-wave pipeline, 8-wave blocks (q-tile 256).
// Grid (4, B*H) = 256 blocks x 512 thr -> 16 waves/CU. Pair {x, 7-x}:
// ktiles per half = 4*qx+4, per block 36 uniform. KVBLK=64 shared by 8 waves.
// LDS (u16): K [0,4608) = [64 key][72 d-pad]; V [4608,9216) same;
// epilogue scratch [0,18432) = 8 waves x 2304.
// S^T = mfma(K,Q): q = lane&31; keys = (reg&3)+8*(reg>>2)+4*(lane>>5) (+32kb).
// Softmax per-lane scalar (m,l); P packed in-register (cvt_pk + permlane32).
// O^T = mfma(V^T via tr-reads, P).  Q prescaled by 0.125*log2e (in weights).
// ---------------------------------------------------------------------------
__global__ __launch_bounds__(512, 4) void attn_kernel(
    const u16* __restrict__ qkv, u16* __restrict__ y)
{
  __shared__ __attribute__((aligned(16))) u16 smem[18432];   // 36.9 KB

  const int tid  = threadIdx.x;
  const int lane = tid & 63;
  const int w    = tid >> 6;          // 0..7
  const int l31  = lane & 31;
  const int hh   = lane >> 5;
  const int l15  = lane & 15;
  const int lh   = lane >> 4;
  const int bh   = blockIdx.y;
  const int b    = bh >> 4;
  const int head = bh & 15;

  const size_t rowbase = (size_t)b * Tt * NQKV;

  // staging map: 16B of one key row per thread (8 threads/row, 64 rows)
  const int skey = tid >> 3;          // 0..63
  const int sp   = tid & 7;           // col sp*8 u16
  const u16* kbase = qkv + rowbase + 1024 + head*64 + sp*8;
  const u16* vbase = qkv + rowbase + 2048 + head*64 + sp*8;

  // V^T tr-read lane address (bytes); V at byte 9216, layout [64][72]
  const unsigned smemB = (unsigned)(size_t)(&smem[0]);
  const unsigned vaddr = smemB + 9216
      + ((lh>>1)*8 + (l15>>2))*144 + (lh&1)*32 + (l15&3)*8;

  for (int half = 0; half < 2; ++half) {
    const int qx    = half ? (7 - (int)blockIdx.x) : (int)blockIdx.x;
    const int qbase = qx * 256;
    const int qw    = qbase + w * 32;
    const int qi    = qw + l31;            // this lane's q row
    const int ktiles = 4*qx + 4;

    // Q fragments (B operand): lane holds Q[qi][m*16 + hh*8 + j]
    bf16x8 qfrag[4];
#pragma unroll
    for (int m = 0; m < 4; ++m)
      qfrag[m] = *(const bf16x8*)(qkv + rowbase + (size_t)qi * NQKV
                                  + head*64 + m*16 + hh*8);

    f32x16 o0 = {}, o1 = {};               // O^T: d 0..31 / d 32..63
    float m_run = -1e30f, l_part = 0.0f;

    uint4 kr0 = *(const uint4*)(kbase + (size_t)skey * NQKV);
    uint4 vr0 = *(const uint4*)(vbase + (size_t)skey * NQKV);

    for (int kt = 0; kt < ktiles; ++kt) {
      __syncthreads();   // prev iter reads / prev half epilogue done
      *(uint4*)&smem[skey*72 + sp*8]        = kr0;
      *(uint4*)&smem[4608 + skey*72 + sp*8] = vr0;
      __syncthreads();

      if (kt + 1 < ktiles) {  // T14: issue next tile's loads before compute
        kr0 = *(const uint4*)(kbase + (size_t)((kt+1)*64 + skey) * NQKV);
        vr0 = *(const uint4*)(vbase + (size_t)((kt+1)*64 + skey) * NQKV);
      }

      if (kt*64 <= qw + 31) {
        // ---- S^T = K Q^T : two 32-key blocks ----
        f32x16 s0 = {}, s1 = {};
#pragma unroll
        for (int m = 0; m < 4; ++m) {
          const int co = m*16 + hh*8;
          bf16x8 k0 = *(const bf16x8*)&smem[(l31)*72      + co];
          bf16x8 k1 = *(const bf16x8*)&smem[(32 + l31)*72 + co];
          s0 = __builtin_amdgcn_mfma_f32_32x32x16_bf16(k0, qfrag[m], s0, 0,0,0);
          s1 = __builtin_amdgcn_mfma_f32_32x32x16_bf16(k1, qfrag[m], s1, 0,0,0);
        }

        // ---- causal mask (diagonal region only) ----
        if (kt*64 + 63 > qw) {
          const int kb0 = kt*64;
#pragma unroll
          for (int r = 0; r < 16; ++r) {
            const int crow = (r&3) + 8*(r>>2) + 4*hh;
            if (kb0 + crow > qi)      s0[r] = -1e30f;
            if (kb0 + 32 + crow > qi) s1[r] = -1e30f;
          }
        }

        // ---- per-lane softmax: in-lane max + one permlane swap ----
        float rm = s0[0];
#pragma unroll
        for (int r = 1; r < 16; ++r) rm = fmaxf(rm, s0[r]);
#pragma unroll
        for (int r = 0; r < 16; ++r) rm = fmaxf(rm, s1[r]);
        {
          uint2v t = plswap(__float_as_uint(rm), __float_as_uint(rm));
          rm = fmaxf(__uint_as_float(t[0]), __uint_as_float(t[1]));
        }
        if (__any(rm > m_run + 8.0f)) {    // defer-max THR=8 (log2 units)
          const float mn = fmaxf(m_run, rm);
          const float al = exp2f(m_run - mn);
          m_run = mn; l_part *= al;
#pragma unroll
          for (int r = 0; r < 16; ++r) { o0[r] *= al; o1[r] *= al; }
        }

        // ---- exp2 + in-register P pack (T12) ----
        pfu pf0, pf1, pf2, pf3;
        {
          float pe[16];
#pragma unroll
          for (int r = 0; r < 16; ++r) { pe[r] = exp2f(s0[r] - m_run); l_part += pe[r]; }
          unsigned a0 = cvtpk(pe[0],pe[1]),  a1 = cvtpk(pe[2],pe[3]);
          unsigned a2 = cvtpk(pe[4],pe[5]),  a3 = cvtpk(pe[6],pe[7]);
          uint2v x1 = plswap(a0, a2), x2 = plswap(a1, a3);
          pf0.u[0]=x1[0]; pf0.u[1]=x2[0]; pf0.u[2]=x1[1]; pf0.u[3]=x2[1];
          unsigned b0 = cvtpk(pe[8],pe[9]),  b1 = cvtpk(pe[10],pe[11]);
          unsigned b2 = cvtpk(pe[12],pe[13]), b3 = cvtpk(pe[14],pe[15]);
          uint2v x3 = plswap(b0, b2), x4 = plswap(b1, b3);
          pf1.u[0]=x3[0]; pf1.u[1]=x4[0]; pf1.u[2]=x3[1]; pf1.u[3]=x4[1];
        }
        {
          float pe[16];
#pragma unroll
          for (int r = 0; r < 16; ++r) { pe[r] = exp2f(s1[r] - m_run); l_part += pe[r]; }
          unsigned a0 = cvtpk(pe[0],pe[1]),  a1 = cvtpk(pe[2],pe[3]);
          unsigned a2 = cvtpk(pe[4],pe[5]),  a3 = cvtpk(pe[6],pe[7]);
          uint2v x1 = plswap(a0, a2), x2 = plswap(a1, a3);
          pf2.u[0]=x1[0]; pf2.u[1]=x2[0]; pf2.u[2]=x1[1]; pf2.u[3]=x2[1];
          unsigned b0 = cvtpk(pe[8],pe[9]),  b1 = cvtpk(pe[10],pe[11]);
          unsigned b2 = cvtpk(pe[12],pe[13]), b3 = cvtpk(pe[14],pe[15]);
          uint2v x3 = plswap(b0, b2), x4 = plswap(b1, b3);
          pf3.u[0]=x3[0]; pf3.u[1]=x4[0]; pf3.u[2]=x3[1]; pf3.u[3]=x4[1];
        }

        // ---- O^T += V^T P : 16 tr-reads, then 8 MFMAs ----
        short4v ta0,tb0,ta1,tb1,ta2,tb2,ta3,tb3,ta4,tb4,ta5,tb5,ta6,tb6,ta7,tb7;
        TRD(ta0, vaddr, "0");    TRD(tb0, vaddr, "576");   // c0 d2=0
        TRD(ta1, vaddr, "64");   TRD(tb1, vaddr, "640");   // c0 d2=1
        TRD(ta2, vaddr, "2304"); TRD(tb2, vaddr, "2880");  // c1 d2=0
        TRD(ta3, vaddr, "2368"); TRD(tb3, vaddr, "2944");  // c1 d2=1
        TRD(ta4, vaddr, "4608"); TRD(tb4, vaddr, "5184");  // c2 d2=0
        TRD(ta5, vaddr, "4672"); TRD(tb5, vaddr, "5248");  // c2 d2=1
        TRD(ta6, vaddr, "6912"); TRD(tb6, vaddr, "7488");  // c3 d2=0
        TRD(ta7, vaddr, "6976"); TRD(tb7, vaddr, "7552");  // c3 d2=1
        asm volatile("s_waitcnt lgkmcnt(0)" ::: "memory");
        __builtin_amdgcn_sched_barrier(0);
        trpair v00,v01,v10,v11,v20,v21,v30,v31;
        v00.h[0]=ta0; v00.h[1]=tb0;  v01.h[0]=ta1; v01.h[1]=tb1;
        v10.h[0]=ta2; v10.h[1]=tb2;  v11.h[0]=ta3; v11.h[1]=tb3;
        v20.h[0]=ta4; v20.h[1]=tb4;  v21.h[0]=ta5; v21.h[1]=tb5;
        v30.h[0]=ta6; v30.h[1]=tb6;  v31.h[0]=ta7; v31.h[1]=tb7;
        o0 = __builtin_amdgcn_mfma_f32_32x32x16_bf16(v00.v, pf0.v, o0, 0,0,0);
        o1 = __builtin_amdgcn_mfma_f32_32x32x16_bf16(v01.v, pf0.v, o1, 0,0,0);
        o0 = __builtin_amdgcn_mfma_f32_32x32x16_bf16(v10.v, pf1.v, o0, 0,0,0);
        o1 = __builtin_amdgcn_mfma_f32_32x32x16_bf16(v11.v, pf1.v, o1, 0,0,0);
        o0 = __builtin_amdgcn_mfma_f32_32x32x16_bf16(v20.v, pf2.v, o0, 0,0,0);
        o1 = __builtin_amdgcn_mfma_f32_32x32x16_bf16(v21.v, pf2.v, o1, 0,0,0);
        o0 = __builtin_amdgcn_mfma_f32_32x32x16_bf16(v30.v, pf3.v, o0, 0,0,0);
        o1 = __builtin_amdgcn_mfma_f32_32x32x16_bf16(v31.v, pf3.v, o1, 0,0,0);
      }
    }

    // ---- epilogue: reduce l, normalize, transpose via LDS, store ----
    {
      uint2v t = plswap(__float_as_uint(l_part), __float_as_uint(l_part));
      l_part = __uint_as_float(t[0]) + __uint_as_float(t[1]);
    }
    const float inv = 1.0f / l_part;

    __syncthreads();   // all waves done with K/V before scratch reuse
#pragma unroll
    for (int k4 = 0; k4 < 4; ++k4) {
      bf16x4 pa, pb;
#pragma unroll
      for (int j = 0; j < 4; ++j) {
        pa[j] = (bf16_t)(o0[4*k4 + j] * inv);
        pb[j] = (bf16_t)(o1[4*k4 + j] * inv);
      }
      *(bf16x4*)&smem[w*2304 + l31*72 +      8*k4 + 4*hh] = pa;
      *(bf16x4*)&smem[w*2304 + l31*72 + 32 + 8*k4 + 4*hh] = pb;
    }
    u16* yp = y + ((size_t)(b*Tt + qi)) * Cc + head*64;
#pragma unroll
    for (int p = 0; p < 4; ++p) {
      bf16x8 row = *(const bf16x8*)&smem[w*2304 + l31*72 + p*16 + hh*8];
      *(bf16x8*)(yp + p*16 + hh*8) = row;
    }
    // next half's loop-top __syncthreads orders scratch reads vs restaging
  }
}

// ---------------------------------------------------------------------------
extern "C" void kernel_launch(void* const* d_in, const int* in_sizes, int n_in,
                              void* d_out, int out_size, void* d_ws, size_t ws_size,
                              hipStream_t stream) {
  const float* x      = (const float*)d_in[0];
  const float* w_attn = (const float*)d_in[1];
  const float* b_attn = (const float*)d_in[2];
  const float* w_proj = (const float*)d_in[3];
  const float* b_proj = (const float*)d_in[4];
  float* out = (float*)d_out;

  char* ws = (char*)d_ws;
  u16*   xb    = (u16*)(ws + 0);          // 16 MB
  u16*   wab   = (u16*)(ws + 16777216);   // 6 MB
  u16*   wpb   = (u16*)(ws + 23068672);   // 2 MB
  u16*   qkvb  = (u16*)(ws + 25165824);   // 48 MB
  u16*   yb    = (u16*)(ws + 75497472);   // 16 MB
  float* sbias = (float*)(ws + 92274688); // 12 KB

  // single-launch conversion (x, w_attn+QSCALE, w_proj, b_attn)
  cvt_all<<<6146, 256, 0, stream>>>(x, w_attn, w_proj, b_attn,
                                    xb, wab, wpb, sbias);

  // 1) QKV projection (bf16 out, q pre-scaled)
  gemm_bf16<1><<<dim3(Mtot/128, NQKV/128), 256, 0, stream>>>(
      xb, wab, sbias, (void*)qkvb, Mtot, NQKV, Cc);

  // 2) causal attention (bf16 y) — 8-wave blocks, 256-row q-tiles, paired
  attn_kernel<<<dim3(4, Bb*Hh), 512, 0, stream>>>(qkvb, yb);

  // 3) output projection (f32 out)
  gemm_bf16<0><<<dim3(Mtot/128, Cc/128), 256, 0, stream>>>(
      yb, wpb, b_proj, (void*)out, Mtot, Cc, Cc);
}

// Round 11
// 181.842 us; speedup vs baseline: 1.2134x; 1.0161x over previous
//
#include <hip/hip_runtime.h>

#define Bb 4
#define Tt 2048
#define Cc 1024
#define Hh 16
#define NQKV 3072
#define Mtot 8192

typedef __bf16 bf16_t;
typedef unsigned short u16;
typedef __bf16 bf16x8 __attribute__((ext_vector_type(8)));
typedef __bf16 bf16x4 __attribute__((ext_vector_type(4)));
typedef short short4v __attribute__((ext_vector_type(4)));
typedef float f32x4 __attribute__((ext_vector_type(4)));
typedef float f32x16 __attribute__((ext_vector_type(16)));
typedef unsigned uint2v __attribute__((ext_vector_type(2)));

union bfu { bf16_t b; u16 u; };
union trpair { short4v h[2]; bf16x8 v; };
union pfu { unsigned u[4]; bf16x8 v; };

#define QSCALE 0.18033688011112042f  /* 0.125 * log2(e) */

// hardware transpose read; "memory" clobber keeps it ordered vs ds_writes
#define TRD(dst, addr, OFF)                                                     \
  asm volatile("ds_read_b64_tr_b16 %0, %1 offset:" OFF                          \
               : "=v"(dst) : "v"(addr) : "memory")

__device__ __forceinline__ unsigned cvtpk(float a, float b) {
  unsigned r;
  asm("v_cvt_pk_bf16_f32 %0, %1, %2" : "=v"(r) : "v"(a), "v"(b));
  return r;
}
__device__ __forceinline__ uint2v plswap(unsigned a, unsigned b) {
  return __builtin_amdgcn_permlane32_swap(a, b, false, false);
}

// ---------------------------------------------------------------------------
// One-launch conversion: x, w_attn (QSCALE on q rows), w_proj -> bf16;
// b_attn -> scaled f32 bias.
// ---------------------------------------------------------------------------
__device__ __forceinline__ void cvt8(const float* s, u16* d, size_t i, float f) {
  float4 a = *(const float4*)(s + i);
  float4 b = *(const float4*)(s + i + 4);
  bf16x8 v;
  v[0]=(bf16_t)(a.x*f); v[1]=(bf16_t)(a.y*f); v[2]=(bf16_t)(a.z*f); v[3]=(bf16_t)(a.w*f);
  v[4]=(bf16_t)(b.x*f); v[5]=(bf16_t)(b.y*f); v[6]=(bf16_t)(b.z*f); v[7]=(bf16_t)(b.w*f);
  *(bf16x8*)(d + i) = v;
}

__global__ __launch_bounds__(256) void cvt_all(
    const float* __restrict__ x, const float* __restrict__ w_attn,
    const float* __restrict__ w_proj, const float* __restrict__ b_attn,
    u16* __restrict__ xb, u16* __restrict__ wab, u16* __restrict__ wpb,
    float* __restrict__ sbias)
{
  const int blk = blockIdx.x;
  if (blk < 4096) {                       // x
    size_t i = ((size_t)blk * 256 + threadIdx.x) * 8;
    cvt8(x, xb, i, 1.0f);
  } else if (blk < 5632) {                // w_attn
    size_t i = ((size_t)(blk - 4096) * 256 + threadIdx.x) * 8;
    cvt8(w_attn, wab, i, (i < (size_t)Cc * Cc) ? QSCALE : 1.0f);
  } else if (blk < 6144) {                // w_proj
    size_t i = ((size_t)(blk - 5632) * 256 + threadIdx.x) * 8;
    cvt8(w_proj, wpb, i, 1.0f);
  } else {                                // b_attn -> sbias
    int i0 = (blk - 6144) * 2048 + threadIdx.x * 8;
#pragma unroll
    for (int j = 0; j < 8; ++j) {
      int i = i0 + j;
      if (i < NQKV) sbias[i] = b_attn[i] * ((i < Cc) ? QSCALE : 1.0f);
    }
  }
}

// ---------------------------------------------------------------------------
// GEMM NT, bf16 inputs, reg-staged with preload (r4 version — fastest measured)
// ---------------------------------------------------------------------------
template <int OUTBF16>
__global__ __launch_bounds__(256) void gemm_bf16(
    const u16* __restrict__ A, const u16* __restrict__ Bm,
    const float* __restrict__ bias, void* __restrict__ Cout,
    int M, int N, int K)
{
  __shared__ __attribute__((aligned(16))) u16 sa[128][40];
  __shared__ __attribute__((aligned(16))) u16 sb[128][40];

  const int tid  = threadIdx.x;
  const int lane = tid & 63;
  const int wid  = tid >> 6;
  const int wr   = (wid >> 1) * 64;
  const int wc   = (wid & 1) * 64;
  const int l15  = lane & 15;
  const int lh   = lane >> 4;
  const int bm   = blockIdx.x * 128;
  const int bn   = blockIdx.y * 128;

  f32x4 acc[4][4] = {};

  const int srow = tid >> 1;
  const int sseg = (tid & 1) * 16;

  const u16* pa = A  + (size_t)(bm + srow) * K + sseg;
  const u16* pb = Bm + (size_t)(bn + srow) * K + sseg;

  uint4 ar0 = *(const uint4*)pa, ar1 = *(const uint4*)(pa + 8);
  uint4 br0 = *(const uint4*)pb, br1 = *(const uint4*)(pb + 8);
  pa += 32; pb += 32;

  for (int k0 = 0; k0 < K; k0 += 32) {
    __syncthreads();
    *(uint4*)&sa[srow][sseg]     = ar0;
    *(uint4*)&sa[srow][sseg + 8] = ar1;
    *(uint4*)&sb[srow][sseg]     = br0;
    *(uint4*)&sb[srow][sseg + 8] = br1;
    __syncthreads();
    if (k0 + 32 < K) {
      ar0 = *(const uint4*)pa; ar1 = *(const uint4*)(pa + 8);
      br0 = *(const uint4*)pb; br1 = *(const uint4*)(pb + 8);
      pa += 32; pb += 32;
    }
    bf16x8 af[4], bfv[4];
#pragma unroll
    for (int mi = 0; mi < 4; mi++)
      af[mi] = *(const bf16x8*)&sa[wr + mi*16 + l15][lh * 8];
#pragma unroll
    for (int ni = 0; ni < 4; ni++)
      bfv[ni] = *(const bf16x8*)&sb[wc + ni*16 + l15][lh * 8];
#pragma unroll
    for (int mi = 0; mi < 4; mi++)
#pragma unroll
      for (int ni = 0; ni < 4; ni++)
        acc[mi][ni] = __builtin_amdgcn_mfma_f32_16x16x32_bf16(
            af[mi], bfv[ni], acc[mi][ni], 0, 0, 0);
  }

#pragma unroll
  for (int mi = 0; mi < 4; mi++) {
#pragma unroll
    for (int ni = 0; ni < 4; ni++) {
      const int col = bn + wc + ni*16 + l15;
      const float bs = bias[col];
#pragma unroll
      for (int r = 0; r < 4; r++) {
        const int row = bm + wr + mi*16 + lh*4 + r;
        const float val = acc[mi][ni][r] + bs;
        if (OUTBF16) {
          bfu cv; cv.b = (bf16_t)val;
          ((u16*)Cout)[(size_t)row * N + col] = cv.u;
        } else {
          ((float*)Cout)[(size_t)row * N + col] = val;
        }
      }
    }
  }
}

// ---------------------------------------------------------------------------
// Causal flash attention: r10 grid/geometry (8-wave blocks, 256-row q-tiles,
// paired {x,7-x}), now with:
//   - 3-buffer K/V rotation -> ONE barrier per k-tile (was 2)
//   - T15 ILP: QK^T(kt+1) issued before softmax/PV(kt); sA/sB ping-pong
//   - tree row-max, 4-way partial l-sums, setprio around MFMA clusters
// LDS: 3 buffers x (K[64][72] + V[64][72]) = 55.3 KB; epilogue scratch overlays.
// ---------------------------------------------------------------------------
#define BUFU 9216   /* u16 per buffer */

__global__ __launch_bounds__(512) void attn_kernel(
    const u16* __restrict__ qkv, u16* __restrict__ y)
{
  __shared__ __attribute__((aligned(16))) u16 smem[3 * BUFU];  // 55.3 KB

  const int tid  = threadIdx.x;
  const int lane = tid & 63;
  const int w    = tid >> 6;          // 0..7
  const int l31  = lane & 31;
  const int hh   = lane >> 5;
  const int l15  = lane & 15;
  const int lh   = lane >> 4;
  const int bh   = blockIdx.y;
  const int b    = bh >> 4;
  const int head = bh & 15;

  const size_t rowbase = (size_t)b * Tt * NQKV;

  // staging map: 16B of one key row per thread (8 threads/row, 64 rows)
  const int skey = tid >> 3;
  const int sp   = tid & 7;
  const u16* kbase = qkv + rowbase + 1024 + head*64 + sp*8;
  const u16* vbase = qkv + rowbase + 2048 + head*64 + sp*8;

  // V^T tr-read lane address base (bytes); add (bofs*2 + 9216) per buffer
  const unsigned smemB = (unsigned)(size_t)(&smem[0]);
  const unsigned trl = smemB
      + ((lh>>1)*8 + (l15>>2))*144 + (lh&1)*32 + (l15&3)*8;

  uint4 kr0, vr0;
#define LOADREGS(t) do {                                                        \
    kr0 = *(const uint4*)(kbase + (size_t)((t)*64 + skey) * NQKV);              \
    vr0 = *(const uint4*)(vbase + (size_t)((t)*64 + skey) * NQKV);              \
  } while (0)
#define STAGEB(bofs) do {                                                       \
    *(uint4*)&smem[(bofs) + skey*72 + sp*8]        = kr0;                       \
    *(uint4*)&smem[(bofs) + 4608 + skey*72 + sp*8] = vr0;                       \
  } while (0)

  for (int half = 0; half < 2; ++half) {
    const int qx    = half ? (7 - (int)blockIdx.x) : (int)blockIdx.x;
    const int qbase = qx * 256;
    const int qw    = qbase + w * 32;
    const int qi    = qw + l31;            // this lane's q row
    const int ktiles = 4*qx + 4;           // even, >= 4

    // Q fragments (B operand)
    bf16x8 qfrag[4];
#pragma unroll
    for (int m = 0; m < 4; ++m)
      qfrag[m] = *(const bf16x8*)(qkv + rowbase + (size_t)qi * NQKV
                                  + head*64 + m*16 + hh*8);

    f32x16 o0 = {}, o1 = {};
    float m_run = -1e30f, l_part = 0.0f;
    f32x16 sA0, sA1, sB0, sB1;

    // ---- QK^T of one 64-key tile from buffer kofs into t0/t1, with mask ----
    auto qk = [&](f32x16& t0, f32x16& t1, int kofs, int kb0) {
      f32x16 a0 = {}, a1 = {};
      __builtin_amdgcn_s_setprio(1);
#pragma unroll
      for (int m = 0; m < 4; ++m) {
        const int co = m*16 + hh*8;
        bf16x8 k0 = *(const bf16x8*)&smem[kofs + l31*72 + co];
        bf16x8 k1 = *(const bf16x8*)&smem[kofs + (32 + l31)*72 + co];
        a0 = __builtin_amdgcn_mfma_f32_32x32x16_bf16(k0, qfrag[m], a0, 0,0,0);
        a1 = __builtin_amdgcn_mfma_f32_32x32x16_bf16(k1, qfrag[m], a1, 0,0,0);
      }
      __builtin_amdgcn_s_setprio(0);
      if (kb0 + 63 > qw) {
#pragma unroll
        for (int r = 0; r < 16; ++r) {
          const int crow = (r&3) + 8*(r>>2) + 4*hh;
          if (kb0 + crow > qi)      a0[r] = -1e30f;
          if (kb0 + 32 + crow > qi) a1[r] = -1e30f;
        }
      }
      t0 = a0; t1 = a1;
    };

    // ---- softmax + PV for the tile whose S sits in s0/s1, V in buffer bofs --
    auto smpv = [&](f32x16& s0, f32x16& s1, int bofs) {
      // tree row-max (depth 5)
      float mx[8];
#pragma unroll
      for (int i = 0; i < 8; ++i)
        mx[i] = fmaxf(fmaxf(s0[i], s0[i+8]), fmaxf(s1[i], s1[i+8]));
#pragma unroll
      for (int i = 0; i < 4; ++i) mx[i] = fmaxf(mx[i], mx[i+4]);
      mx[0] = fmaxf(mx[0], mx[2]); mx[1] = fmaxf(mx[1], mx[3]);
      float rm = fmaxf(mx[0], mx[1]);
      {
        uint2v t = plswap(__float_as_uint(rm), __float_as_uint(rm));
        rm = fmaxf(__uint_as_float(t[0]), __uint_as_float(t[1]));
      }
      if (__any(rm > m_run + 8.0f)) {      // defer-max THR=8 (log2 units)
        const float mn = fmaxf(m_run, rm);
        const float al = exp2f(m_run - mn);
        m_run = mn; l_part *= al;
#pragma unroll
        for (int r = 0; r < 16; ++r) { o0[r] *= al; o1[r] *= al; }
      }

      pfu pf0, pf1, pf2, pf3;
      float lp0 = 0.f, lp1 = 0.f, lp2 = 0.f, lp3 = 0.f;
      {
        float pe[16];
#pragma unroll
        for (int r = 0; r < 16; ++r) pe[r] = exp2f(s0[r] - m_run);
#pragma unroll
        for (int r = 0; r < 4; ++r) {
          lp0 += pe[r]; lp1 += pe[4+r]; lp2 += pe[8+r]; lp3 += pe[12+r];
        }
        unsigned a0 = cvtpk(pe[0],pe[1]),  a1 = cvtpk(pe[2],pe[3]);
        unsigned a2 = cvtpk(pe[4],pe[5]),  a3 = cvtpk(pe[6],pe[7]);
        uint2v x1 = plswap(a0, a2), x2 = plswap(a1, a3);
        pf0.u[0]=x1[0]; pf0.u[1]=x2[0]; pf0.u[2]=x1[1]; pf0.u[3]=x2[1];
        unsigned b0 = cvtpk(pe[8],pe[9]),  b1 = cvtpk(pe[10],pe[11]);
        unsigned b2 = cvtpk(pe[12],pe[13]), b3 = cvtpk(pe[14],pe[15]);
        uint2v x3 = plswap(b0, b2), x4 = plswap(b1, b3);
        pf1.u[0]=x3[0]; pf1.u[1]=x4[0]; pf1.u[2]=x3[1]; pf1.u[3]=x4[1];
      }
      {
        float pe[16];
#pragma unroll
        for (int r = 0; r < 16; ++r) pe[r] = exp2f(s1[r] - m_run);
#pragma unroll
        for (int r = 0; r < 4; ++r) {
          lp0 += pe[r]; lp1 += pe[4+r]; lp2 += pe[8+r]; lp3 += pe[12+r];
        }
        unsigned a0 = cvtpk(pe[0],pe[1]),  a1 = cvtpk(pe[2],pe[3]);
        unsigned a2 = cvtpk(pe[4],pe[5]),  a3 = cvtpk(pe[6],pe[7]);
        uint2v x1 = plswap(a0, a2), x2 = plswap(a1, a3);
        pf2.u[0]=x1[0]; pf2.u[1]=x2[0]; pf2.u[2]=x1[1]; pf2.u[3]=x2[1];
        unsigned b0 = cvtpk(pe[8],pe[9]),  b1 = cvtpk(pe[10],pe[11]);
        unsigned b2 = cvtpk(pe[12],pe[13]), b3 = cvtpk(pe[14],pe[15]);
        uint2v x3 = plswap(b0, b2), x4 = plswap(b1, b3);
        pf3.u[0]=x3[0]; pf3.u[1]=x4[0]; pf3.u[2]=x3[1]; pf3.u[3]=x4[1];
      }
      l_part += (lp0 + lp1) + (lp2 + lp3);

      const unsigned va = trl + (unsigned)(bofs*2 + 9216);
      short4v ta0,tb0,ta1,tb1,ta2,tb2,ta3,tb3,ta4,tb4,ta5,tb5,ta6,tb6,ta7,tb7;
      TRD(ta0, va, "0");    TRD(tb0, va, "576");
      TRD(ta1, va, "64");   TRD(tb1, va, "640");
      TRD(ta2, va, "2304"); TRD(tb2, va, "2880");
      TRD(ta3, va, "2368"); TRD(tb3, va, "2944");
      TRD(ta4, va, "4608"); TRD(tb4, va, "5184");
      TRD(ta5, va, "4672"); TRD(tb5, va, "5248");
      TRD(ta6, va, "6912"); TRD(tb6, va, "7488");
      TRD(ta7, va, "6976"); TRD(tb7, va, "7552");
      asm volatile("s_waitcnt lgkmcnt(0)" ::: "memory");
      __builtin_amdgcn_sched_barrier(0);
      trpair v00,v01,v10,v11,v20,v21,v30,v31;
      v00.h[0]=ta0; v00.h[1]=tb0;  v01.h[0]=ta1; v01.h[1]=tb1;
      v10.h[0]=ta2; v10.h[1]=tb2;  v11.h[0]=ta3; v11.h[1]=tb3;
      v20.h[0]=ta4; v20.h[1]=tb4;  v21.h[0]=ta5; v21.h[1]=tb5;
      v30.h[0]=ta6; v30.h[1]=tb6;  v31.h[0]=ta7; v31.h[1]=tb7;
      __builtin_amdgcn_s_setprio(1);
      o0 = __builtin_amdgcn_mfma_f32_32x32x16_bf16(v00.v, pf0.v, o0, 0,0,0);
      o1 = __builtin_amdgcn_mfma_f32_32x32x16_bf16(v01.v, pf0.v, o1, 0,0,0);
      o0 = __builtin_amdgcn_mfma_f32_32x32x16_bf16(v10.v, pf1.v, o0, 0,0,0);
      o1 = __builtin_amdgcn_mfma_f32_32x32x16_bf16(v11.v, pf1.v, o1, 0,0,0);
      o0 = __builtin_amdgcn_mfma_f32_32x32x16_bf16(v20.v, pf2.v, o0, 0,0,0);
      o1 = __builtin_amdgcn_mfma_f32_32x32x16_bf16(v21.v, pf2.v, o1, 0,0,0);
      o0 = __builtin_amdgcn_mfma_f32_32x32x16_bf16(v30.v, pf3.v, o0, 0,0,0);
      o1 = __builtin_amdgcn_mfma_f32_32x32x16_bf16(v31.v, pf3.v, o1, 0,0,0);
      __builtin_amdgcn_s_setprio(0);
    };

    // ---- prologue: t0 -> b0, t1 -> b1, t2 in regs; sA = QK(t0) ----
    LOADREGS(0);
    __syncthreads();                 // prev-half readers of smem done
    STAGEB(0);
    LOADREGS(1);
    __syncthreads();                 // b0 ready
    qk(sA0, sA1, 0, 0);              // tile 0 always in range
    STAGEB(BUFU);
    LOADREGS(2);

    int cofs = 0, nofs = BUFU, fofs = 2*BUFU;

    // ---- main loop: one barrier per tile; unrolled x2 for sA/sB roles ----
    for (int kt = 0; kt < ktiles; kt += 2) {
      // part A: tile kt (S in sA), QK of tile kt+1 -> sB
      __syncthreads();
      if ((kt+1)*64 <= qw + 31) qk(sB0, sB1, nofs, (kt+1)*64);
      if (kt*64 <= qw + 31)     smpv(sA0, sA1, cofs);
      if (kt + 2 < ktiles) {
        STAGEB(fofs);
        if (kt + 3 < ktiles) LOADREGS(kt + 3);
      }
      { int t = cofs; cofs = nofs; nofs = fofs; fofs = t; }

      // part B: tile kt+1 (S in sB), QK of tile kt+2 -> sA
      __syncthreads();
      if ((kt+2) < ktiles && (kt+2)*64 <= qw + 31) qk(sA0, sA1, nofs, (kt+2)*64);
      if ((kt+1)*64 <= qw + 31) smpv(sB0, sB1, cofs);
      if (kt + 3 < ktiles) {
        STAGEB(fofs);
        if (kt + 4 < ktiles) LOADREGS(kt + 4);
      }
      { int t = cofs; cofs = nofs; nofs = fofs; fofs = t; }
    }

    // ---- epilogue: reduce l, normalize, transpose via LDS, store ----
    {
      uint2v t = plswap(__float_as_uint(l_part), __float_as_uint(l_part));
      l_part = __uint_as_float(t[0]) + __uint_as_float(t[1]);
    }
    const float inv = 1.0f / l_part;

    __syncthreads();   // all waves done with K/V before scratch reuse
#pragma unroll
    for (int k4 = 0; k4 < 4; ++k4) {
      bf16x4 pa, pb;
#pragma unroll
      for (int j = 0; j < 4; ++j) {
        pa[j] = (bf16_t)(o0[4*k4 + j] * inv);
        pb[j] = (bf16_t)(o1[4*k4 + j] * inv);
      }
      *(bf16x4*)&smem[w*2304 + l31*72 +      8*k4 + 4*hh] = pa;
      *(bf16x4*)&smem[w*2304 + l31*72 + 32 + 8*k4 + 4*hh] = pb;
    }
    u16* yp = y + ((size_t)(b*Tt + qi)) * Cc + head*64;
#pragma unroll
    for (int p = 0; p < 4; ++p) {
      bf16x8 row = *(const bf16x8*)&smem[w*2304 + l31*72 + p*16 + hh*8];
      *(bf16x8*)(yp + p*16 + hh*8) = row;
    }
    // next half's prologue barrier orders scratch reads vs restaging
  }
#undef LOADREGS
#undef STAGEB
}

// ---------------------------------------------------------------------------
extern "C" void kernel_launch(void* const* d_in, const int* in_sizes, int n_in,
                              void* d_out, int out_size, void* d_ws, size_t ws_size,
                              hipStream_t stream) {
  const float* x      = (const float*)d_in[0];
  const float* w_attn = (const float*)d_in[1];
  const float* b_attn = (const float*)d_in[2];
  const float* w_proj = (const float*)d_in[3];
  const float* b_proj = (const float*)d_in[4];
  float* out = (float*)d_out;

  char* ws = (char*)d_ws;
  u16*   xb    = (u16*)(ws + 0);          // 16 MB
  u16*   wab   = (u16*)(ws + 16777216);   // 6 MB
  u16*   wpb   = (u16*)(ws + 23068672);   // 2 MB
  u16*   qkvb  = (u16*)(ws + 25165824);   // 48 MB
  u16*   yb    = (u16*)(ws + 75497472);   // 16 MB
  float* sbias = (float*)(ws + 92274688); // 12 KB

  // single-launch conversion (x, w_attn+QSCALE, w_proj, b_attn)
  cvt_all<<<6146, 256, 0, stream>>>(x, w_attn, w_proj, b_attn,
                                    xb, wab, wpb, sbias);

  // 1) QKV projection (bf16 out, q pre-scaled)
  gemm_bf16<1><<<dim3(Mtot/128, NQKV/128), 256, 0, stream>>>(
      xb, wab, sbias, (void*)qkvb, Mtot, NQKV, Cc);

  // 2) causal attention (bf16 y)
  attn_kernel<<<dim3(4, Bb*Hh), 512, 0, stream>>>(qkvb, yb);

  // 3) output projection (f32 out)
  gemm_bf16<0><<<dim3(Mtot/128, Cc/128), 256, 0, stream>>>(
      yb, wpb, b_proj, (void*)out, Mtot, Cc, Cc);
}